// Round 3
// baseline (374.384 us; speedup 1.0000x reference)
//
#include <hip/hip_runtime.h>
#include <hip/hip_bf16.h>

#define N_NODES 100000
#define E_EDGES 640000
// channels: IN 256, HID 128, OUT 64+64

typedef __attribute__((ext_vector_type(8))) short short8;
typedef __attribute__((ext_vector_type(4))) float float4v;

__device__ __forceinline__ float bf2f(unsigned int u16) {
    union { unsigned int i; float f; } c; c.i = u16 << 16; return c.f;
}
__device__ __forceinline__ unsigned short f2bf(float f) {
    union { float f; unsigned int i; } c; c.f = f;
    unsigned int x = c.i;
    unsigned int r = (x + 0x7fffu + ((x >> 16) & 1u)) >> 16;   // RNE
    return (unsigned short)r;
}

// ---------------- workspace layout (bytes) ----------------
#define WS_HIST    0          // int[100000]
#define WS_CURSOR  524288     // int[100000]   (memset together with hist)
#define WS_OFFS    1048576    // int[100000]
#define WS_DINV    1572864    // float[100000]
#define WS_BSUMS   2097152    // int[256]
#define WS_EIDX    2621440    // int2[640000]  {src, bits(weight)}
#define WS_WP1     7864320    // bf16[128][256] packed W1^T
#define WS_WP2     7929856    // bf16[128][128] packed [Wmu|Wlv]^T
#define WS_H0      7962624    // bf16[100000*128]  x@W1, reused as g after agg2
#define WS_H       33562624   // bf16[100000*128]  relu(A_hat h0 + b1)

// ---------------- setup: histogram + weight pack (fused, independent work) ----
#define NB_E 2500
__global__ __launch_bounds__(256) void k_hist_pack(const int* __restrict__ dst, int* __restrict__ hist,
                                                   const float* __restrict__ W1,
                                                   const float* __restrict__ Wmu,
                                                   const float* __restrict__ Wlv,
                                                   unsigned short* __restrict__ Wp1,
                                                   unsigned short* __restrict__ Wp2) {
    int b = blockIdx.x;
    if (b < NB_E) {
        int e = b * 256 + threadIdx.x;
        if (e < E_EDGES) atomicAdd(&hist[dst[e]], 1);
    } else {
        int i = (b - NB_E) * 256 + threadIdx.x;
        if (i < 256 * 128) {
            int k = i >> 7, n = i & 127;
            Wp1[n * 256 + k] = f2bf(W1[i]);
        }
        if (i < 128 * 128) {
            int k = i >> 7, n = i & 127;
            float w = (n < 64) ? Wmu[k * 64 + n] : Wlv[k * 64 + (n - 64)];
            Wp2[n * 128 + k] = f2bf(w);
        }
    }
}

// scan level 1 (+ dinv computed on the side)
__global__ __launch_bounds__(256) void k_scan1(const int* __restrict__ hist,
                                               int* __restrict__ offs,
                                               int* __restrict__ bsums,
                                               float* __restrict__ dinv) {
    __shared__ int sd[256];
    int t = threadIdx.x;
    int base = blockIdx.x * 1024 + t * 4;
    int v[4];
#pragma unroll
    for (int j = 0; j < 4; ++j) v[j] = (base + j < N_NODES) ? hist[base + j] : 0;
#pragma unroll
    for (int j = 0; j < 4; ++j)
        if (base + j < N_NODES) dinv[base + j] = rsqrtf((float)(v[j] + 1));
    int s = v[0] + v[1] + v[2] + v[3];
    sd[t] = s;
    __syncthreads();
    for (int d = 1; d < 256; d <<= 1) {
        int x = (t >= d) ? sd[t - d] : 0;
        __syncthreads();
        sd[t] += x;
        __syncthreads();
    }
    int excl = sd[t] - s;
    if (t == 255) bsums[blockIdx.x] = sd[255];
    int run = excl;
#pragma unroll
    for (int j = 0; j < 4; ++j) {
        if (base + j < N_NODES) offs[base + j] = run;
        run += v[j];
    }
}

__global__ __launch_bounds__(128) void k_scan2(int* __restrict__ bsums, int nb) {
    __shared__ int sd[128];
    int t = threadIdx.x;
    int v = (t < nb) ? bsums[t] : 0;
    sd[t] = v;
    __syncthreads();
    for (int d = 1; d < 128; d <<= 1) {
        int x = (t >= d) ? sd[t - d] : 0;
        __syncthreads();
        sd[t] += x;
        __syncthreads();
    }
    if (t < nb) bsums[t] = sd[t] - v;
}

// CSR fill; global offset = offs[d] + bsums[d>>10] folded here
__global__ __launch_bounds__(256) void k_fill(const int* __restrict__ src, const int* __restrict__ dst,
                                              const int* __restrict__ offs, const int* __restrict__ bsums,
                                              int* __restrict__ cursor,
                                              const float* __restrict__ dinv,
                                              int2* __restrict__ eidx) {
    int e = blockIdx.x * 256 + threadIdx.x;
    if (e < E_EDGES) {
        int s = src[e], d = dst[e];
        int p = offs[d] + bsums[d >> 10] + atomicAdd(&cursor[d], 1);
        int2 v;
        v.x = s;
        v.y = __float_as_int(dinv[s] * dinv[d]);
        eidx[p] = v;
    }
}

// ---------------- GEMM1: h0[N][128] = bf16(x[N][256]) @ W1 ----------------
// Barrier-free, LDS-free register GEMM. Same block tile (64 rows x 128 cols,
// sequential blockIdx -> compact L3 footprint) and same epilogue as round 2;
// the one change: A and B fragments load global->VGPR directly (B is 64 KB,
// L2-resident; A loads in exact MFMA lane layout). Fully-unrolled K-loop gives
// the compiler ~48 independent VMEM ops per wave to pipeline -- no vmcnt(0)
// drains, no __syncthreads. Tests the barrier-serialization theory.
__global__ __launch_bounds__(256) void k_mgemm1(const float* __restrict__ A,
                                                const unsigned short* __restrict__ Bpack,
                                                unsigned short* __restrict__ out) {
    int tid = threadIdx.x;
    int row0 = blockIdx.x * 64;
    int wave = tid >> 6, lane = tid & 63;
    int c = lane & 15, q = lane >> 4;
    int wrow = (wave >> 1) * 32, wcol = (wave & 1) * 64;

    float4v acc[2][4];
#pragma unroll
    for (int i = 0; i < 2; ++i)
#pragma unroll
        for (int j = 0; j < 4; ++j) acc[i][j] = (float4v){0.f, 0.f, 0.f, 0.f};

    // group validity is uniform per (block, wave, mt): N % 16 == 0
    bool val[2];
    const float* aptr[2];
#pragma unroll
    for (int mt = 0; mt < 2; ++mt) {
        int base = row0 + wrow + mt * 16;
        val[mt] = (base < N_NODES);
        int r = val[mt] ? (base + c) : 0;
        aptr[mt] = A + (size_t)r * 256 + q * 8;
    }
    const unsigned short* bptr[4];
#pragma unroll
    for (int nt = 0; nt < 4; ++nt)
        bptr[nt] = Bpack + (size_t)(wcol + nt * 16 + c) * 256 + q * 8;

#pragma unroll
    for (int kc = 0; kc < 8; ++kc) {
        short8 af[2], bfr[4];
#pragma unroll
        for (int nt = 0; nt < 4; ++nt)
            bfr[nt] = *(const short8*)(bptr[nt] + kc * 32);
#pragma unroll
        for (int mt = 0; mt < 2; ++mt) {
            float4v fa = (float4v){0.f, 0.f, 0.f, 0.f};
            float4v fb = (float4v){0.f, 0.f, 0.f, 0.f};
            if (val[mt]) {
                fa = *(const float4v*)(aptr[mt] + kc * 32);
                fb = *(const float4v*)(aptr[mt] + kc * 32 + 4);
            }
            short8 s;
#pragma unroll
            for (int jj = 0; jj < 4; ++jj) {
                s[jj]     = (short)f2bf(fa[jj]);
                s[4 + jj] = (short)f2bf(fb[jj]);
            }
            af[mt] = s;
        }
#pragma unroll
        for (int mt = 0; mt < 2; ++mt)
#pragma unroll
            for (int nt = 0; nt < 4; ++nt)
                acc[mt][nt] = __builtin_amdgcn_mfma_f32_16x16x32_bf16(af[mt], bfr[nt], acc[mt][nt], 0, 0, 0);
    }

    // epilogue: bf16 out. D: col = lane&15, row = q*4 + reg
#pragma unroll
    for (int mt = 0; mt < 2; ++mt) {
        if (!val[mt]) continue;
#pragma unroll
        for (int i = 0; i < 4; ++i) {
            int row = row0 + wrow + mt * 16 + q * 4 + i;
#pragma unroll
            for (int nt = 0; nt < 4; ++nt) {
                int cc = wcol + nt * 16 + c;
                out[(size_t)row * 128 + cc] = f2bf(acc[mt][nt][i]);
            }
        }
    }
}

// ---------------- GEMM2: [mu|logvar] = g[N][128] @ W2 + bias, fp32 out -------
// Same barrier-free register structure; A already bf16 -> one 16B load per frag.
__global__ __launch_bounds__(256) void k_mgemm2(const unsigned short* __restrict__ A,
                                                const unsigned short* __restrict__ Bpack,
                                                const float* __restrict__ bias0,
                                                const float* __restrict__ bias1,
                                                float* __restrict__ out) {
    int tid = threadIdx.x;
    int row0 = blockIdx.x * 64;
    int wave = tid >> 6, lane = tid & 63;
    int c = lane & 15, q = lane >> 4;
    int wrow = (wave >> 1) * 32, wcol = (wave & 1) * 64;

    float4v acc[2][4];
#pragma unroll
    for (int i = 0; i < 2; ++i)
#pragma unroll
        for (int j = 0; j < 4; ++j) acc[i][j] = (float4v){0.f, 0.f, 0.f, 0.f};

    bool val[2];
    const unsigned short* aptr[2];
#pragma unroll
    for (int mt = 0; mt < 2; ++mt) {
        int base = row0 + wrow + mt * 16;
        val[mt] = (base < N_NODES);
        int r = val[mt] ? (base + c) : 0;
        aptr[mt] = A + (size_t)r * 128 + q * 8;
    }
    const unsigned short* bptr[4];
#pragma unroll
    for (int nt = 0; nt < 4; ++nt)
        bptr[nt] = Bpack + (size_t)(wcol + nt * 16 + c) * 128 + q * 8;

#pragma unroll
    for (int kc = 0; kc < 4; ++kc) {
        short8 af[2], bfr[4];
#pragma unroll
        for (int nt = 0; nt < 4; ++nt)
            bfr[nt] = *(const short8*)(bptr[nt] + kc * 32);
#pragma unroll
        for (int mt = 0; mt < 2; ++mt) {
            short8 a = {0, 0, 0, 0, 0, 0, 0, 0};
            if (val[mt]) a = *(const short8*)(aptr[mt] + kc * 32);
            af[mt] = a;
        }
#pragma unroll
        for (int mt = 0; mt < 2; ++mt)
#pragma unroll
            for (int nt = 0; nt < 4; ++nt)
                acc[mt][nt] = __builtin_amdgcn_mfma_f32_16x16x32_bf16(af[mt], bfr[nt], acc[mt][nt], 0, 0, 0);
    }

    // epilogue: mu at 0, logvar at N*64
#pragma unroll
    for (int mt = 0; mt < 2; ++mt) {
        if (!val[mt]) continue;
#pragma unroll
        for (int i = 0; i < 4; ++i) {
            int row = row0 + wrow + mt * 16 + q * 4 + i;
#pragma unroll
            for (int nt = 0; nt < 4; ++nt) {
                int cc = wcol + nt * 16 + c;
                float v = acc[mt][nt][i];
                if (cc < 64) out[(size_t)row * 64 + cc] = v + bias0[cc];
                else out[(size_t)N_NODES * 64 + (size_t)row * 64 + (cc - 64)] = v + bias1[cc - 64];
            }
        }
    }
}

// ---------------- aggregation: one wave per node, lane-parallel edge prefetch ----
template <int BIAS_RELU>
__global__ __launch_bounds__(256) void k_agg(const unsigned int* __restrict__ in,
                                             unsigned int* __restrict__ out,
                                             const float* __restrict__ dinv,
                                             const int2* __restrict__ eidx,
                                             const int* __restrict__ offs,
                                             const int* __restrict__ bsums,
                                             const int* __restrict__ cnt,
                                             const float* __restrict__ bias) {
    int wid = (blockIdx.x * 256 + threadIdx.x) >> 6;
    if (wid >= N_NODES) return;
    int l = threadIdx.x & 63;
    float di = dinv[wid];
    unsigned int u = in[(size_t)wid * 64 + l];
    float sc = di * di;
    float ax = sc * bf2f(u & 0xffffu);
    float ay = sc * bf2f(u >> 16);
    if (BIAS_RELU) { ax += bias[2 * l]; ay += bias[2 * l + 1]; }
    int start = offs[wid] + bsums[wid >> 10];
    int n = cnt[wid];

    for (int base = 0; base < n; base += 64) {
        int m = min(n - base, 64);
        int sreg = 0; float wreg = 0.f;
        if (l < m) {
            int2 ev = eidx[start + base + l];
            sreg = ev.x;
            wreg = __int_as_float(ev.y);
        }
        int e = 0;
        for (; e + 4 <= m; e += 4) {
            int s0 = __shfl(sreg, e),     s1 = __shfl(sreg, e + 1);
            int s2 = __shfl(sreg, e + 2), s3 = __shfl(sreg, e + 3);
            float w0 = __shfl(wreg, e),     w1 = __shfl(wreg, e + 1);
            float w2 = __shfl(wreg, e + 2), w3 = __shfl(wreg, e + 3);
            unsigned int u0 = in[(size_t)s0 * 64 + l];
            unsigned int u1 = in[(size_t)s1 * 64 + l];
            unsigned int u2 = in[(size_t)s2 * 64 + l];
            unsigned int u3 = in[(size_t)s3 * 64 + l];
            ax += w0 * bf2f(u0 & 0xffffu); ay += w0 * bf2f(u0 >> 16);
            ax += w1 * bf2f(u1 & 0xffffu); ay += w1 * bf2f(u1 >> 16);
            ax += w2 * bf2f(u2 & 0xffffu); ay += w2 * bf2f(u2 >> 16);
            ax += w3 * bf2f(u3 & 0xffffu); ay += w3 * bf2f(u3 >> 16);
        }
        for (; e < m; ++e) {
            int s0 = __shfl(sreg, e);
            float w0 = __shfl(wreg, e);
            unsigned int u0 = in[(size_t)s0 * 64 + l];
            ax += w0 * bf2f(u0 & 0xffffu); ay += w0 * bf2f(u0 >> 16);
        }
    }
    if (BIAS_RELU) { ax = fmaxf(ax, 0.f); ay = fmaxf(ay, 0.f); }
    out[(size_t)wid * 64 + l] = (unsigned int)f2bf(ax) | ((unsigned int)f2bf(ay) << 16);
}

// ---------------- launch ----------------
extern "C" void kernel_launch(void* const* d_in, const int* in_sizes, int n_in,
                              void* d_out, int out_size, void* d_ws, size_t ws_size,
                              hipStream_t stream) {
    const float* x    = (const float*)d_in[0];
    const int*   ei   = (const int*)d_in[1];
    const float* W1   = (const float*)d_in[2];
    const float* b1   = (const float*)d_in[3];
    const float* Wmu  = (const float*)d_in[4];
    const float* bmu  = (const float*)d_in[5];
    const float* Wlv  = (const float*)d_in[6];
    const float* blv  = (const float*)d_in[7];
    float* outp = (float*)d_out;

    const int* src = ei;
    const int* dst = ei + E_EDGES;

    char* ws = (char*)d_ws;
    int*            hist   = (int*)(ws + WS_HIST);
    int*            cursor = (int*)(ws + WS_CURSOR);
    int*            offs   = (int*)(ws + WS_OFFS);
    float*          dinv   = (float*)(ws + WS_DINV);
    int*            bsums  = (int*)(ws + WS_BSUMS);
    int2*           eidx   = (int2*)(ws + WS_EIDX);
    unsigned short* Wp1    = (unsigned short*)(ws + WS_WP1);
    unsigned short* Wp2    = (unsigned short*)(ws + WS_WP2);
    unsigned short* h0     = (unsigned short*)(ws + WS_H0);   // x@W1, reused as g
    unsigned short* h      = (unsigned short*)(ws + WS_H);    // relu(A_hat h0 + b1)

    const int NB_S = (N_NODES + 1023) / 1024;   // 98
    const int NB_G = (N_NODES + 63) / 64;       // 1563

    hipMemsetAsync(ws + WS_HIST, 0, 1048576, stream);   // hist + cursor
    k_hist_pack<<<NB_E + 128, 256, 0, stream>>>(dst, hist, W1, Wmu, Wlv, Wp1, Wp2);
    k_scan1<<<NB_S, 256, 0, stream>>>(hist, offs, bsums, dinv);
    k_scan2<<<1, 128, 0, stream>>>(bsums, NB_S);
    k_fill<<<NB_E, 256, 0, stream>>>(src, dst, offs, bsums, cursor, dinv, eidx);

    // layer 1: h0 = bf16(x) @ W1 ; h = relu(A_hat h0 + b1)
    k_mgemm1<<<NB_G, 256, 0, stream>>>(x, Wp1, h0);
    k_agg<1><<<(N_NODES * 64 + 255) / 256, 256, 0, stream>>>(
        (const unsigned int*)h0, (unsigned int*)h, dinv, eidx, offs, bsums, hist, b1);

    // layers 2+3: g = A_hat h (h already relu'd) ; [mu|logvar] = g @ W2 + bias
    k_agg<0><<<(N_NODES * 64 + 255) / 256, 256, 0, stream>>>(
        (const unsigned int*)h, (unsigned int*)h0, dinv, eidx, offs, bsums, hist, nullptr);
    k_mgemm2<<<NB_G, 256, 0, stream>>>(h0, Wp2, bmu, blv, outp);
}

// Round 4
// 364.325 us; speedup vs baseline: 1.0276x; 1.0276x over previous
//
#include <hip/hip_runtime.h>
#include <hip/hip_bf16.h>

#define N_NODES 100000
#define E_EDGES 640000
// channels: IN 256, HID 128, OUT 64+64

typedef __attribute__((ext_vector_type(8))) short short8;
typedef __attribute__((ext_vector_type(4))) float float4v;

__device__ __forceinline__ float bf2f(unsigned int u16) {
    union { unsigned int i; float f; } c; c.i = u16 << 16; return c.f;
}
__device__ __forceinline__ unsigned short f2bf(float f) {
    union { float f; unsigned int i; } c; c.f = f;
    unsigned int x = c.i;
    unsigned int r = (x + 0x7fffu + ((x >> 16) & 1u)) >> 16;   // RNE
    return (unsigned short)r;
}

// ---------------- workspace layout (bytes) ----------------
#define WS_HIST    0          // int[100000]
#define WS_CURSOR  524288     // int[100000]   (memset together with hist)
#define WS_OFFS    1048576    // int[100000]
#define WS_DINV    1572864    // float[100000]
#define WS_BSUMS   2097152    // int[256]
#define WS_EIDX    2621440    // int2[640000]  {src, bits(weight)}
#define WS_WP1     7864320    // bf16[128][256] packed W1^T
#define WS_WP2     7929856    // bf16[128][128] packed [Wmu|Wlv]^T
#define WS_H0      7962624    // bf16[100000*128]  x@W1, reused as g after agg2
#define WS_H       33562624   // bf16[100000*128]  relu(A_hat h0 + b1)
#define WS_XB      59162624   // bf16[100000*256]  bf16(x)  (+51.2 MB)

// ---------------- setup: histogram + weight pack + x->bf16 stream ----------
// The x->bf16 convert blocks are also the BW probe: pure float4->short8 stream.
#define NB_E   2500
#define NB_CVT 12500          // 3,200,000 short8 groups / 256
__global__ __launch_bounds__(256) void k_hist_pack(const int* __restrict__ dst, int* __restrict__ hist,
                                                   const float* __restrict__ W1,
                                                   const float* __restrict__ Wmu,
                                                   const float* __restrict__ Wlv,
                                                   unsigned short* __restrict__ Wp1,
                                                   unsigned short* __restrict__ Wp2,
                                                   const float* __restrict__ x,
                                                   unsigned short* __restrict__ xb) {
    int b = blockIdx.x;
    if (b < NB_E) {
        int e = b * 256 + threadIdx.x;
        if (e < E_EDGES) atomicAdd(&hist[dst[e]], 1);
    } else if (b < NB_E + 128) {
        int i = (b - NB_E) * 256 + threadIdx.x;
        if (i < 256 * 128) {
            int k = i >> 7, n = i & 127;
            Wp1[n * 256 + k] = f2bf(W1[i]);
        }
        if (i < 128 * 128) {
            int k = i >> 7, n = i & 127;
            float w = (n < 64) ? Wmu[k * 64 + n] : Wlv[k * 64 + (n - 64)];
            Wp2[n * 128 + k] = f2bf(w);
        }
    } else {
        int i = (b - NB_E - 128) * 256 + threadIdx.x;   // short8 group index
        if (i < N_NODES * 32) {                          // 25.6M elems / 8
            const float* p = x + (size_t)i * 8;
            float4v a0 = *(const float4v*)(p);
            float4v a1 = *(const float4v*)(p + 4);
            short8 v;
#pragma unroll
            for (int j = 0; j < 4; ++j) {
                v[j]     = (short)f2bf(a0[j]);
                v[4 + j] = (short)f2bf(a1[j]);
            }
            *(short8*)(xb + (size_t)i * 8) = v;
        }
    }
}

// scan level 1 (+ dinv computed on the side)
__global__ __launch_bounds__(256) void k_scan1(const int* __restrict__ hist,
                                               int* __restrict__ offs,
                                               int* __restrict__ bsums,
                                               float* __restrict__ dinv) {
    __shared__ int sd[256];
    int t = threadIdx.x;
    int base = blockIdx.x * 1024 + t * 4;
    int v[4];
#pragma unroll
    for (int j = 0; j < 4; ++j) v[j] = (base + j < N_NODES) ? hist[base + j] : 0;
#pragma unroll
    for (int j = 0; j < 4; ++j)
        if (base + j < N_NODES) dinv[base + j] = rsqrtf((float)(v[j] + 1));
    int s = v[0] + v[1] + v[2] + v[3];
    sd[t] = s;
    __syncthreads();
    for (int d = 1; d < 256; d <<= 1) {
        int x = (t >= d) ? sd[t - d] : 0;
        __syncthreads();
        sd[t] += x;
        __syncthreads();
    }
    int excl = sd[t] - s;
    if (t == 255) bsums[blockIdx.x] = sd[255];
    int run = excl;
#pragma unroll
    for (int j = 0; j < 4; ++j) {
        if (base + j < N_NODES) offs[base + j] = run;
        run += v[j];
    }
}

__global__ __launch_bounds__(128) void k_scan2(int* __restrict__ bsums, int nb) {
    __shared__ int sd[128];
    int t = threadIdx.x;
    int v = (t < nb) ? bsums[t] : 0;
    sd[t] = v;
    __syncthreads();
    for (int d = 1; d < 128; d <<= 1) {
        int x = (t >= d) ? sd[t - d] : 0;
        __syncthreads();
        sd[t] += x;
        __syncthreads();
    }
    if (t < nb) bsums[t] = sd[t] - v;
}

// CSR fill; global offset = offs[d] + bsums[d>>10] folded here
__global__ __launch_bounds__(256) void k_fill(const int* __restrict__ src, const int* __restrict__ dst,
                                              const int* __restrict__ offs, const int* __restrict__ bsums,
                                              int* __restrict__ cursor,
                                              const float* __restrict__ dinv,
                                              int2* __restrict__ eidx) {
    int e = blockIdx.x * 256 + threadIdx.x;
    if (e < E_EDGES) {
        int s = src[e], d = dst[e];
        int p = offs[d] + bsums[d >> 10] + atomicAdd(&cursor[d], 1);
        int2 v;
        v.x = s;
        v.y = __float_as_int(dinv[s] * dinv[d]);
        eidx[p] = v;
    }
}

// ---------------- GEMM1: h0[N][128] = xb[N][256] @ W1 (bf16 A path) ---------
// Round-2 mgemm2 structure (proven best) with K=256: A now pre-converted bf16
// from workspace (half the read bytes of the old fp32 path, L3-hot).
__global__ __launch_bounds__(256, 6) void k_mgemm1(const unsigned short* __restrict__ A,
                                                   const unsigned short* __restrict__ Bpack,
                                                   unsigned short* __restrict__ out) {
    constexpr int LDT = 40;
    __shared__ unsigned short As[64 * LDT];    // 5 KB
    __shared__ unsigned short Bs[128 * LDT];   // 10 KB
    int tid = threadIdx.x;
    int row0 = blockIdx.x * 64;
    int wave = tid >> 6, lane = tid & 63;
    int c = lane & 15, q = lane >> 4;
    int wrow = (wave >> 1) * 32, wcol = (wave & 1) * 64;

    float4v acc[2][4];
#pragma unroll
    for (int i = 0; i < 2; ++i)
#pragma unroll
        for (int j = 0; j < 4; ++j) acc[i][j] = (float4v){0.f, 0.f, 0.f, 0.f};

    int srow = tid >> 1, shalf = (tid & 1) * 16;   // B stage (128 rows x 32 k)
    int arow = tid >> 2, aoff = (tid & 3) * 8;     // A stage (64 rows x 32 k)
    const short8 zed = {0, 0, 0, 0, 0, 0, 0, 0};

    for (int k0 = 0; k0 < 256; k0 += 32) {
        const unsigned short* bsrc = Bpack + (size_t)srow * 256 + k0 + shalf;
        short8 b0 = *(const short8*)(bsrc);
        short8 b1 = *(const short8*)(bsrc + 8);
        int grow = row0 + arow;
        short8 a0 = zed;
        if (grow < N_NODES)
            a0 = *(const short8*)(A + (size_t)grow * 256 + k0 + aoff);
        *(short8*)(&Bs[srow * LDT + shalf])     = b0;
        *(short8*)(&Bs[srow * LDT + shalf + 8]) = b1;
        *(short8*)(&As[arow * LDT + aoff])      = a0;
        __syncthreads();

        short8 af[2], bfr[4];
#pragma unroll
        for (int mt = 0; mt < 2; ++mt)
            af[mt] = *(const short8*)(&As[(wrow + mt * 16 + c) * LDT + q * 8]);
#pragma unroll
        for (int nt = 0; nt < 4; ++nt)
            bfr[nt] = *(const short8*)(&Bs[(wcol + nt * 16 + c) * LDT + q * 8]);
#pragma unroll
        for (int mt = 0; mt < 2; ++mt)
#pragma unroll
            for (int nt = 0; nt < 4; ++nt)
                acc[mt][nt] = __builtin_amdgcn_mfma_f32_16x16x32_bf16(af[mt], bfr[nt], acc[mt][nt], 0, 0, 0);
        __syncthreads();
    }

    // epilogue: bf16 out. D: col = lane&15, row = q*4 + reg
#pragma unroll
    for (int mt = 0; mt < 2; ++mt) {
#pragma unroll
        for (int i = 0; i < 4; ++i) {
            int row = row0 + wrow + mt * 16 + q * 4 + i;
            if (row >= N_NODES) continue;
#pragma unroll
            for (int nt = 0; nt < 4; ++nt) {
                int cc = wcol + nt * 16 + c;
                out[(size_t)row * 128 + cc] = f2bf(acc[mt][nt][i]);
            }
        }
    }
}

// ---------------- GEMM2: [mu|logvar] = g[N][128] @ W2 + bias, fp32 out -------
// Round-2 version, untouched.
__global__ __launch_bounds__(256, 6) void k_mgemm2(const unsigned short* __restrict__ A,
                                                   const unsigned short* __restrict__ Bpack,
                                                   const float* __restrict__ bias0,
                                                   const float* __restrict__ bias1,
                                                   float* __restrict__ out) {
    constexpr int LDT = 40;
    __shared__ unsigned short As[64 * LDT];    // 5 KB
    __shared__ unsigned short Bs[128 * LDT];   // 10 KB
    int tid = threadIdx.x;
    int row0 = blockIdx.x * 64;
    int wave = tid >> 6, lane = tid & 63;
    int c = lane & 15, q = lane >> 4;
    int wrow = (wave >> 1) * 32, wcol = (wave & 1) * 64;

    float4v acc[2][4];
#pragma unroll
    for (int i = 0; i < 2; ++i)
#pragma unroll
        for (int j = 0; j < 4; ++j) acc[i][j] = (float4v){0.f, 0.f, 0.f, 0.f};

    int srow = tid >> 1, shalf = (tid & 1) * 16;   // B stage (128 rows x 32 k)
    int arow = tid >> 2, aoff = (tid & 3) * 8;     // A stage (64 rows x 32 k)
    const short8 zed = {0, 0, 0, 0, 0, 0, 0, 0};

    for (int k0 = 0; k0 < 128; k0 += 32) {
        const unsigned short* bsrc = Bpack + (size_t)srow * 128 + k0 + shalf;
        short8 b0 = *(const short8*)(bsrc);
        short8 b1 = *(const short8*)(bsrc + 8);
        int grow = row0 + arow;
        short8 a0 = zed;
        if (grow < N_NODES)
            a0 = *(const short8*)(A + (size_t)grow * 128 + k0 + aoff);
        *(short8*)(&Bs[srow * LDT + shalf])     = b0;
        *(short8*)(&Bs[srow * LDT + shalf + 8]) = b1;
        *(short8*)(&As[arow * LDT + aoff])      = a0;
        __syncthreads();

        short8 af[2], bfr[4];
#pragma unroll
        for (int mt = 0; mt < 2; ++mt)
            af[mt] = *(const short8*)(&As[(wrow + mt * 16 + c) * LDT + q * 8]);
#pragma unroll
        for (int nt = 0; nt < 4; ++nt)
            bfr[nt] = *(const short8*)(&Bs[(wcol + nt * 16 + c) * LDT + q * 8]);
#pragma unroll
        for (int mt = 0; mt < 2; ++mt)
#pragma unroll
            for (int nt = 0; nt < 4; ++nt)
                acc[mt][nt] = __builtin_amdgcn_mfma_f32_16x16x32_bf16(af[mt], bfr[nt], acc[mt][nt], 0, 0, 0);
        __syncthreads();
    }

    // epilogue: mu at 0, logvar at N*64
#pragma unroll
    for (int mt = 0; mt < 2; ++mt) {
#pragma unroll
        for (int i = 0; i < 4; ++i) {
            int row = row0 + wrow + mt * 16 + q * 4 + i;
            if (row >= N_NODES) continue;
#pragma unroll
            for (int nt = 0; nt < 4; ++nt) {
                int cc = wcol + nt * 16 + c;
                float v = acc[mt][nt][i];
                if (cc < 64) out[(size_t)row * 64 + cc] = v + bias0[cc];
                else out[(size_t)N_NODES * 64 + (size_t)row * 64 + (cc - 64)] = v + bias1[cc - 64];
            }
        }
    }
}

// ---------------- aggregation: one wave per node, lane-parallel edge prefetch ----
template <int BIAS_RELU>
__global__ __launch_bounds__(256) void k_agg(const unsigned int* __restrict__ in,
                                             unsigned int* __restrict__ out,
                                             const float* __restrict__ dinv,
                                             const int2* __restrict__ eidx,
                                             const int* __restrict__ offs,
                                             const int* __restrict__ bsums,
                                             const int* __restrict__ cnt,
                                             const float* __restrict__ bias) {
    int wid = (blockIdx.x * 256 + threadIdx.x) >> 6;
    if (wid >= N_NODES) return;
    int l = threadIdx.x & 63;
    float di = dinv[wid];
    unsigned int u = in[(size_t)wid * 64 + l];
    float sc = di * di;
    float ax = sc * bf2f(u & 0xffffu);
    float ay = sc * bf2f(u >> 16);
    if (BIAS_RELU) { ax += bias[2 * l]; ay += bias[2 * l + 1]; }
    int start = offs[wid] + bsums[wid >> 10];
    int n = cnt[wid];

    for (int base = 0; base < n; base += 64) {
        int m = min(n - base, 64);
        int sreg = 0; float wreg = 0.f;
        if (l < m) {
            int2 ev = eidx[start + base + l];
            sreg = ev.x;
            wreg = __int_as_float(ev.y);
        }
        int e = 0;
        for (; e + 4 <= m; e += 4) {
            int s0 = __shfl(sreg, e),     s1 = __shfl(sreg, e + 1);
            int s2 = __shfl(sreg, e + 2), s3 = __shfl(sreg, e + 3);
            float w0 = __shfl(wreg, e),     w1 = __shfl(wreg, e + 1);
            float w2 = __shfl(wreg, e + 2), w3 = __shfl(wreg, e + 3);
            unsigned int u0 = in[(size_t)s0 * 64 + l];
            unsigned int u1 = in[(size_t)s1 * 64 + l];
            unsigned int u2 = in[(size_t)s2 * 64 + l];
            unsigned int u3 = in[(size_t)s3 * 64 + l];
            ax += w0 * bf2f(u0 & 0xffffu); ay += w0 * bf2f(u0 >> 16);
            ax += w1 * bf2f(u1 & 0xffffu); ay += w1 * bf2f(u1 >> 16);
            ax += w2 * bf2f(u2 & 0xffffu); ay += w2 * bf2f(u2 >> 16);
            ax += w3 * bf2f(u3 & 0xffffu); ay += w3 * bf2f(u3 >> 16);
        }
        for (; e < m; ++e) {
            int s0 = __shfl(sreg, e);
            float w0 = __shfl(wreg, e);
            unsigned int u0 = in[(size_t)s0 * 64 + l];
            ax += w0 * bf2f(u0 & 0xffffu); ay += w0 * bf2f(u0 >> 16);
        }
    }
    if (BIAS_RELU) { ax = fmaxf(ax, 0.f); ay = fmaxf(ay, 0.f); }
    out[(size_t)wid * 64 + l] = (unsigned int)f2bf(ax) | ((unsigned int)f2bf(ay) << 16);
}

// ---------------- launch ----------------
extern "C" void kernel_launch(void* const* d_in, const int* in_sizes, int n_in,
                              void* d_out, int out_size, void* d_ws, size_t ws_size,
                              hipStream_t stream) {
    const float* x    = (const float*)d_in[0];
    const int*   ei   = (const int*)d_in[1];
    const float* W1   = (const float*)d_in[2];
    const float* b1   = (const float*)d_in[3];
    const float* Wmu  = (const float*)d_in[4];
    const float* bmu  = (const float*)d_in[5];
    const float* Wlv  = (const float*)d_in[6];
    const float* blv  = (const float*)d_in[7];
    float* outp = (float*)d_out;

    const int* src = ei;
    const int* dst = ei + E_EDGES;

    char* ws = (char*)d_ws;
    int*            hist   = (int*)(ws + WS_HIST);
    int*            cursor = (int*)(ws + WS_CURSOR);
    int*            offs   = (int*)(ws + WS_OFFS);
    float*          dinv   = (float*)(ws + WS_DINV);
    int*            bsums  = (int*)(ws + WS_BSUMS);
    int2*           eidx   = (int2*)(ws + WS_EIDX);
    unsigned short* Wp1    = (unsigned short*)(ws + WS_WP1);
    unsigned short* Wp2    = (unsigned short*)(ws + WS_WP2);
    unsigned short* h0     = (unsigned short*)(ws + WS_H0);   // x@W1, reused as g
    unsigned short* h      = (unsigned short*)(ws + WS_H);    // relu(A_hat h0 + b1)
    unsigned short* xb     = (unsigned short*)(ws + WS_XB);   // bf16(x)

    const int NB_S = (N_NODES + 1023) / 1024;   // 98
    const int NB_G = (N_NODES + 63) / 64;       // 1563

    hipMemsetAsync(ws + WS_HIST, 0, 1048576, stream);   // hist + cursor
    k_hist_pack<<<NB_E + 128 + NB_CVT, 256, 0, stream>>>(dst, hist, W1, Wmu, Wlv, Wp1, Wp2, x, xb);
    k_scan1<<<NB_S, 256, 0, stream>>>(hist, offs, bsums, dinv);
    k_scan2<<<1, 128, 0, stream>>>(bsums, NB_S);
    k_fill<<<NB_E, 256, 0, stream>>>(src, dst, offs, bsums, cursor, dinv, eidx);

    // layer 1: h0 = xb @ W1 ; h = relu(A_hat h0 + b1)
    k_mgemm1<<<NB_G, 256, 0, stream>>>(xb, Wp1, h0);
    k_agg<1><<<(N_NODES * 64 + 255) / 256, 256, 0, stream>>>(
        (const unsigned int*)h0, (unsigned int*)h, dinv, eidx, offs, bsums, hist, b1);

    // layers 2+3: g = A_hat h (h already relu'd) ; [mu|logvar] = g @ W2 + bias
    k_agg<0><<<(N_NODES * 64 + 255) / 256, 256, 0, stream>>>(
        (const unsigned int*)h, (unsigned int*)h0, dinv, eidx, offs, bsums, hist, nullptr);
    k_mgemm2<<<NB_G, 256, 0, stream>>>(h0, Wp2, bmu, blv, outp);
}

// Round 6
// 345.576 us; speedup vs baseline: 1.0834x; 1.0543x over previous
//
#include <hip/hip_runtime.h>
#include <hip/hip_bf16.h>

#define N_NODES 100000
#define E_EDGES 640000
// channels: IN 256, HID 128, OUT 64+64

typedef __attribute__((ext_vector_type(8))) short short8;
typedef __attribute__((ext_vector_type(4))) float float4v;

__device__ __forceinline__ float bf2f(unsigned int u16) {
    union { unsigned int i; float f; } c; c.i = u16 << 16; return c.f;
}
__device__ __forceinline__ unsigned short f2bf(float f) {
    union { float f; unsigned int i; } c; c.f = f;
    unsigned int x = c.i;
    unsigned int r = (x + 0x7fffu + ((x >> 16) & 1u)) >> 16;   // RNE
    return (unsigned short)r;
}

// async 16B global->LDS; aux = CPol bits (bit1 = NT). Applied ONLY to pure
// inputs (x): NT on anything cached-dirty (workspace/output) is a correctness
// hazard -- round-5 failure: NT stores to d_out were clobbered by later
// evictions of dirty poison lines the harness fill left in L2/L3.
#define ASYNC16NT(g, l)                                                        \
    __builtin_amdgcn_global_load_lds(                                          \
        (const __attribute__((address_space(1))) void*)(g),                    \
        (__attribute__((address_space(3))) void*)(l), 16, 0, 2)

// ---------------- workspace layout (bytes) ----------------
#define WS_HIST    0          // int[100000]
#define WS_CURSOR  524288     // int[100000]   (memset together with hist)
#define WS_OFFS    1048576    // int[100000]
#define WS_DINV    1572864    // float[100000]
#define WS_BSUMS   2097152    // int[256]
#define WS_EIDX    2621440    // int2[640000]  {src, bits(weight)}
#define WS_WP1     7864320    // bf16[128][256] packed W1^T
#define WS_WP2     7929856    // bf16[128][128] packed [Wmu|Wlv]^T
#define WS_H0      7962624    // bf16[100000*128]  x@W1, reused as g after agg2
#define WS_H       33562624   // bf16[100000*128]  relu(A_hat h0 + b1)

// ---------------- setup: histogram + weight pack (fused, independent work) ----
#define NB_E 2500
__global__ __launch_bounds__(256) void k_hist_pack(const int* __restrict__ dst, int* __restrict__ hist,
                                                   const float* __restrict__ W1,
                                                   const float* __restrict__ Wmu,
                                                   const float* __restrict__ Wlv,
                                                   unsigned short* __restrict__ Wp1,
                                                   unsigned short* __restrict__ Wp2) {
    int b = blockIdx.x;
    if (b < NB_E) {
        int e = b * 256 + threadIdx.x;
        if (e < E_EDGES) atomicAdd(&hist[__builtin_nontemporal_load(dst + e)], 1);
    } else {
        int i = (b - NB_E) * 256 + threadIdx.x;
        if (i < 256 * 128) {
            int k = i >> 7, n = i & 127;
            Wp1[n * 256 + k] = f2bf(W1[i]);
        }
        if (i < 128 * 128) {
            int k = i >> 7, n = i & 127;
            float w = (n < 64) ? Wmu[k * 64 + n] : Wlv[k * 64 + (n - 64)];
            Wp2[n * 128 + k] = f2bf(w);
        }
    }
}

// scan level 1 (+ dinv computed on the side)
__global__ __launch_bounds__(256) void k_scan1(const int* __restrict__ hist,
                                               int* __restrict__ offs,
                                               int* __restrict__ bsums,
                                               float* __restrict__ dinv) {
    __shared__ int sd[256];
    int t = threadIdx.x;
    int base = blockIdx.x * 1024 + t * 4;
    int v[4];
#pragma unroll
    for (int j = 0; j < 4; ++j) v[j] = (base + j < N_NODES) ? hist[base + j] : 0;
#pragma unroll
    for (int j = 0; j < 4; ++j)
        if (base + j < N_NODES) dinv[base + j] = rsqrtf((float)(v[j] + 1));
    int s = v[0] + v[1] + v[2] + v[3];
    sd[t] = s;
    __syncthreads();
    for (int d = 1; d < 256; d <<= 1) {
        int x = (t >= d) ? sd[t - d] : 0;
        __syncthreads();
        sd[t] += x;
        __syncthreads();
    }
    int excl = sd[t] - s;
    if (t == 255) bsums[blockIdx.x] = sd[255];
    int run = excl;
#pragma unroll
    for (int j = 0; j < 4; ++j) {
        if (base + j < N_NODES) offs[base + j] = run;
        run += v[j];
    }
}

__global__ __launch_bounds__(128) void k_scan2(int* __restrict__ bsums, int nb) {
    __shared__ int sd[128];
    int t = threadIdx.x;
    int v = (t < nb) ? bsums[t] : 0;
    sd[t] = v;
    __syncthreads();
    for (int d = 1; d < 128; d <<= 1) {
        int x = (t >= d) ? sd[t - d] : 0;
        __syncthreads();
        sd[t] += x;
        __syncthreads();
    }
    if (t < nb) bsums[t] = sd[t] - v;
}

// CSR fill; global offset = offs[d] + bsums[d>>10] folded here
__global__ __launch_bounds__(256) void k_fill(const int* __restrict__ src, const int* __restrict__ dst,
                                              const int* __restrict__ offs, const int* __restrict__ bsums,
                                              int* __restrict__ cursor,
                                              const float* __restrict__ dinv,
                                              int2* __restrict__ eidx) {
    int e = blockIdx.x * 256 + threadIdx.x;
    if (e < E_EDGES) {
        int s = __builtin_nontemporal_load(src + e);
        int d = __builtin_nontemporal_load(dst + e);
        int p = offs[d] + bsums[d >> 10] + atomicAdd(&cursor[d], 1);
        int2 v;
        v.x = s;
        v.y = __float_as_int(dinv[s] * dinv[d]);
        eidx[p] = v;
    }
}

// ---------------- GEMM1: h0[N][128] = bf16(x[N][256]) @ W1 ----------------
// Round-2 structure verbatim; single change: A-tile global_load_lds carries
// the NT bit (aux=2). x is a pure input read exactly once -- skipping cache
// allocation avoids forcing evictions of the dirty poison lines in L3 (the
// competing-writeback theory of the universal ~1.5 TB/s read wall).
__global__ __launch_bounds__(256, 6) void k_mgemm1(const float* __restrict__ A,
                                                   const unsigned short* __restrict__ Bpack,
                                                   unsigned short* __restrict__ out) {
    __shared__ float As[64 * 32];           // 8 KB, one K-chunk, swizzled
    __shared__ unsigned short Bs[128 * 40]; // 10 KB, padded stride 40
    int tid = threadIdx.x;
    int row0 = blockIdx.x * 64;
    int wave = tid >> 6, lane = tid & 63;
    int c = lane & 15, q = lane >> 4;
    int wrow = (wave >> 1) * 32, wcol = (wave & 1) * 64;

    float4v acc[2][4];
#pragma unroll
    for (int i = 0; i < 2; ++i)
#pragma unroll
        for (int j = 0; j < 4; ++j) acc[i][j] = (float4v){0.f, 0.f, 0.f, 0.f};

    int srow = tid >> 1;          // B stage: n-row
    int shalf = (tid & 1) * 16;   // B stage: k half

    for (int k0 = 0; k0 < 256; k0 += 32) {
        const unsigned short* bsrc = Bpack + (size_t)srow * 256 + k0 + shalf;
        short8 b0 = *(const short8*)(bsrc);
        short8 b1 = *(const short8*)(bsrc + 8);
#pragma unroll
        for (int t = 0; t < 2; ++t) {
            int grp = t * 4 + wave;               // 8 groups of 64 granules
            int S = grp * 64 + lane;              // slot in [0, 512)
            int row = S >> 3, j = S & 7;
            int kq = j ^ (row & 7);
            const float* g = A + (size_t)(row0 + row) * 256 + k0 + kq * 4;
            float* ldst = As + grp * 256;         // wave-uniform base
            if (row0 + row < N_NODES) ASYNC16NT(g, ldst);
        }
        *(short8*)(&Bs[srow * 40 + shalf])     = b0;
        *(short8*)(&Bs[srow * 40 + shalf + 8]) = b1;
        __syncthreads();

        short8 af[2], bfr[4];
#pragma unroll
        for (int mt = 0; mt < 2; ++mt) {
            int r = wrow + mt * 16 + c;
            int j0 = (q * 2) ^ (r & 7);
            float4v fa = *(const float4v*)(&As[r * 32 + j0 * 4]);        // k = q*8..+3
            float4v fb = *(const float4v*)(&As[r * 32 + (j0 ^ 1) * 4]);  // k = q*8+4..+7
            short8 s;
#pragma unroll
            for (int jj = 0; jj < 4; ++jj) s[jj]     = (short)f2bf(fa[jj]);
#pragma unroll
            for (int jj = 0; jj < 4; ++jj) s[4 + jj] = (short)f2bf(fb[jj]);
            af[mt] = s;
        }
#pragma unroll
        for (int nt = 0; nt < 4; ++nt)
            bfr[nt] = *(const short8*)(&Bs[(wcol + nt * 16 + c) * 40 + q * 8]);
#pragma unroll
        for (int mt = 0; mt < 2; ++mt)
#pragma unroll
            for (int nt = 0; nt < 4; ++nt)
                acc[mt][nt] = __builtin_amdgcn_mfma_f32_16x16x32_bf16(af[mt], bfr[nt], acc[mt][nt], 0, 0, 0);
        __syncthreads();
    }

    // epilogue: bf16 out. D: col = lane&15, row = q*4 + reg
#pragma unroll
    for (int mt = 0; mt < 2; ++mt) {
#pragma unroll
        for (int i = 0; i < 4; ++i) {
            int row = row0 + wrow + mt * 16 + q * 4 + i;
            if (row >= N_NODES) continue;
#pragma unroll
            for (int nt = 0; nt < 4; ++nt) {
                int cc = wcol + nt * 16 + c;
                out[(size_t)row * 128 + cc] = f2bf(acc[mt][nt][i]);
            }
        }
    }
}

// ---------------- GEMM2: [mu|logvar] = g[N][128] @ W2 + bias, fp32 out -------
// Round-2 version, untouched (regular stores: NT stores into the poisoned
// output buffer get clobbered by later dirty-line evictions -- round-5 bug).
__global__ __launch_bounds__(256, 6) void k_mgemm2(const unsigned short* __restrict__ A,
                                                   const unsigned short* __restrict__ Bpack,
                                                   const float* __restrict__ bias0,
                                                   const float* __restrict__ bias1,
                                                   float* __restrict__ out) {
    constexpr int LDT = 40;
    __shared__ unsigned short As[64 * LDT];    // 5 KB
    __shared__ unsigned short Bs[128 * LDT];   // 10 KB
    int tid = threadIdx.x;
    int row0 = blockIdx.x * 64;
    int wave = tid >> 6, lane = tid & 63;
    int c = lane & 15, q = lane >> 4;
    int wrow = (wave >> 1) * 32, wcol = (wave & 1) * 64;

    float4v acc[2][4];
#pragma unroll
    for (int i = 0; i < 2; ++i)
#pragma unroll
        for (int j = 0; j < 4; ++j) acc[i][j] = (float4v){0.f, 0.f, 0.f, 0.f};

    int srow = tid >> 1, shalf = (tid & 1) * 16;   // B stage (128 rows x 32 k)
    int arow = tid >> 2, aoff = (tid & 3) * 8;     // A stage (64 rows x 32 k)
    const short8 zed = {0, 0, 0, 0, 0, 0, 0, 0};

    for (int k0 = 0; k0 < 128; k0 += 32) {
        const unsigned short* bsrc = Bpack + (size_t)srow * 128 + k0 + shalf;
        short8 b0 = *(const short8*)(bsrc);
        short8 b1 = *(const short8*)(bsrc + 8);
        int grow = row0 + arow;
        short8 a0 = zed;
        if (grow < N_NODES)
            a0 = *(const short8*)(A + (size_t)grow * 128 + k0 + aoff);
        *(short8*)(&Bs[srow * LDT + shalf])     = b0;
        *(short8*)(&Bs[srow * LDT + shalf + 8]) = b1;
        *(short8*)(&As[arow * LDT + aoff])      = a0;
        __syncthreads();

        short8 af[2], bfr[4];
#pragma unroll
        for (int mt = 0; mt < 2; ++mt)
            af[mt] = *(const short8*)(&As[(wrow + mt * 16 + c) * LDT + q * 8]);
#pragma unroll
        for (int nt = 0; nt < 4; ++nt)
            bfr[nt] = *(const short8*)(&Bs[(wcol + nt * 16 + c) * LDT + q * 8]);
#pragma unroll
        for (int mt = 0; mt < 2; ++mt)
#pragma unroll
            for (int nt = 0; nt < 4; ++nt)
                acc[mt][nt] = __builtin_amdgcn_mfma_f32_16x16x32_bf16(af[mt], bfr[nt], acc[mt][nt], 0, 0, 0);
        __syncthreads();
    }

    // epilogue: mu at 0, logvar at N*64
#pragma unroll
    for (int mt = 0; mt < 2; ++mt) {
#pragma unroll
        for (int i = 0; i < 4; ++i) {
            int row = row0 + wrow + mt * 16 + q * 4 + i;
            if (row >= N_NODES) continue;
#pragma unroll
            for (int nt = 0; nt < 4; ++nt) {
                int cc = wcol + nt * 16 + c;
                float v = acc[mt][nt][i];
                if (cc < 64) out[(size_t)row * 64 + cc] = v + bias0[cc];
                else out[(size_t)N_NODES * 64 + (size_t)row * 64 + (cc - 64)] = v + bias1[cc - 64];
            }
        }
    }
}

// ---------------- aggregation: one wave per node, lane-parallel edge prefetch ----
template <int BIAS_RELU>
__global__ __launch_bounds__(256) void k_agg(const unsigned int* __restrict__ in,
                                             unsigned int* __restrict__ out,
                                             const float* __restrict__ dinv,
                                             const int2* __restrict__ eidx,
                                             const int* __restrict__ offs,
                                             const int* __restrict__ bsums,
                                             const int* __restrict__ cnt,
                                             const float* __restrict__ bias) {
    int wid = (blockIdx.x * 256 + threadIdx.x) >> 6;
    if (wid >= N_NODES) return;
    int l = threadIdx.x & 63;
    float di = dinv[wid];
    unsigned int u = in[(size_t)wid * 64 + l];
    float sc = di * di;
    float ax = sc * bf2f(u & 0xffffu);
    float ay = sc * bf2f(u >> 16);
    if (BIAS_RELU) { ax += bias[2 * l]; ay += bias[2 * l + 1]; }
    int start = offs[wid] + bsums[wid >> 10];
    int n = cnt[wid];

    for (int base = 0; base < n; base += 64) {
        int m = min(n - base, 64);
        int sreg = 0; float wreg = 0.f;
        if (l < m) {
            int2 ev = eidx[start + base + l];
            sreg = ev.x;
            wreg = __int_as_float(ev.y);
        }
        int e = 0;
        for (; e + 4 <= m; e += 4) {
            int s0 = __shfl(sreg, e),     s1 = __shfl(sreg, e + 1);
            int s2 = __shfl(sreg, e + 2), s3 = __shfl(sreg, e + 3);
            float w0 = __shfl(wreg, e),     w1 = __shfl(wreg, e + 1);
            float w2 = __shfl(wreg, e + 2), w3 = __shfl(wreg, e + 3);
            unsigned int u0 = in[(size_t)s0 * 64 + l];
            unsigned int u1 = in[(size_t)s1 * 64 + l];
            unsigned int u2 = in[(size_t)s2 * 64 + l];
            unsigned int u3 = in[(size_t)s3 * 64 + l];
            ax += w0 * bf2f(u0 & 0xffffu); ay += w0 * bf2f(u0 >> 16);
            ax += w1 * bf2f(u1 & 0xffffu); ay += w1 * bf2f(u1 >> 16);
            ax += w2 * bf2f(u2 & 0xffffu); ay += w2 * bf2f(u2 >> 16);
            ax += w3 * bf2f(u3 & 0xffffu); ay += w3 * bf2f(u3 >> 16);
        }
        for (; e < m; ++e) {
            int s0 = __shfl(sreg, e);
            float w0 = __shfl(wreg, e);
            unsigned int u0 = in[(size_t)s0 * 64 + l];
            ax += w0 * bf2f(u0 & 0xffffu); ay += w0 * bf2f(u0 >> 16);
        }
    }
    if (BIAS_RELU) { ax = fmaxf(ax, 0.f); ay = fmaxf(ay, 0.f); }
    out[(size_t)wid * 64 + l] = (unsigned int)f2bf(ax) | ((unsigned int)f2bf(ay) << 16);
}

// ---------------- launch ----------------
extern "C" void kernel_launch(void* const* d_in, const int* in_sizes, int n_in,
                              void* d_out, int out_size, void* d_ws, size_t ws_size,
                              hipStream_t stream) {
    const float* x    = (const float*)d_in[0];
    const int*   ei   = (const int*)d_in[1];
    const float* W1   = (const float*)d_in[2];
    const float* b1   = (const float*)d_in[3];
    const float* Wmu  = (const float*)d_in[4];
    const float* bmu  = (const float*)d_in[5];
    const float* Wlv  = (const float*)d_in[6];
    const float* blv  = (const float*)d_in[7];
    float* outp = (float*)d_out;

    const int* src = ei;
    const int* dst = ei + E_EDGES;

    char* ws = (char*)d_ws;
    int*            hist   = (int*)(ws + WS_HIST);
    int*            cursor = (int*)(ws + WS_CURSOR);
    int*            offs   = (int*)(ws + WS_OFFS);
    float*          dinv   = (float*)(ws + WS_DINV);
    int*            bsums  = (int*)(ws + WS_BSUMS);
    int2*           eidx   = (int2*)(ws + WS_EIDX);
    unsigned short* Wp1    = (unsigned short*)(ws + WS_WP1);
    unsigned short* Wp2    = (unsigned short*)(ws + WS_WP2);
    unsigned short* h0     = (unsigned short*)(ws + WS_H0);   // x@W1, reused as g
    unsigned short* h      = (unsigned short*)(ws + WS_H);    // relu(A_hat h0 + b1)

    const int NB_S = (N_NODES + 1023) / 1024;   // 98
    const int NB_G = (N_NODES + 63) / 64;       // 1563

    hipMemsetAsync(ws + WS_HIST, 0, 1048576, stream);   // hist + cursor
    k_hist_pack<<<NB_E + 128, 256, 0, stream>>>(dst, hist, W1, Wmu, Wlv, Wp1, Wp2);
    k_scan1<<<NB_S, 256, 0, stream>>>(hist, offs, bsums, dinv);
    k_scan2<<<1, 128, 0, stream>>>(bsums, NB_S);
    k_fill<<<NB_E, 256, 0, stream>>>(src, dst, offs, bsums, cursor, dinv, eidx);

    // layer 1: h0 = bf16(x) @ W1 ; h = relu(A_hat h0 + b1)
    k_mgemm1<<<NB_G, 256, 0, stream>>>(x, Wp1, h0);
    k_agg<1><<<(N_NODES * 64 + 255) / 256, 256, 0, stream>>>(
        (const unsigned int*)h0, (unsigned int*)h, dinv, eidx, offs, bsums, hist, b1);

    // layers 2+3: g = A_hat h (h already relu'd) ; [mu|logvar] = g @ W2 + bias
    k_agg<0><<<(N_NODES * 64 + 255) / 256, 256, 0, stream>>>(
        (const unsigned int*)h, (unsigned int*)h0, dinv, eidx, offs, bsums, hist, nullptr);
    k_mgemm2<<<NB_G, 256, 0, stream>>>(h0, Wp2, bmu, blv, outp);
}

// Round 7
// 339.081 us; speedup vs baseline: 1.1041x; 1.0192x over previous
//
#include <hip/hip_runtime.h>
#include <hip/hip_bf16.h>

#define N_NODES 100000
#define E_EDGES 640000
// channels: IN 256, HID 128, OUT 64+64

typedef __attribute__((ext_vector_type(8))) short short8;
typedef __attribute__((ext_vector_type(4))) float float4v;

__device__ __forceinline__ float bf2f(unsigned int u16) {
    union { unsigned int i; float f; } c; c.i = u16 << 16; return c.f;
}
__device__ __forceinline__ unsigned short f2bf(float f) {
    union { float f; unsigned int i; } c; c.f = f;
    unsigned int x = c.i;
    unsigned int r = (x + 0x7fffu + ((x >> 16) & 1u)) >> 16;   // RNE
    return (unsigned short)r;
}

// async 16B global->LDS; aux = CPol bits (bit1 = NT). ONLY on pure inputs (x):
// NT on cache-dirty buffers (workspace/output) is a correctness hazard (round 5).
#define ASYNC16NT(g, l)                                                        \
    __builtin_amdgcn_global_load_lds(                                          \
        (const __attribute__((address_space(1))) void*)(g),                    \
        (__attribute__((address_space(3))) void*)(l), 16, 0, 2)

// ---------------- workspace layout (bytes) ----------------
#define WS_HIST    0          // int[100000]
#define WS_CURSOR  524288     // int[100000]   (memset together with hist)
#define WS_OFFS    1048576    // int[100000]
#define WS_DINV    1572864    // float[100000]
#define WS_BSUMS   2097152    // int[256]
#define WS_EIDX    2621440    // int2[640000]  {src, bits(weight)}
#define WS_WP1     7864320    // bf16[128][256] packed W1^T
#define WS_WP2     7929856    // bf16[128][128] packed [Wmu|Wlv]^T
#define WS_H0      7962624    // bf16[100000*128]  x@W1
#define WS_H       33562624   // bf16[100000*128]  relu(A_hat h0 + b1)

// ---------------- setup: histogram + weight pack (fused, independent work) ----
#define NB_E 2500
__global__ __launch_bounds__(256) void k_hist_pack(const int* __restrict__ dst, int* __restrict__ hist,
                                                   const float* __restrict__ W1,
                                                   const float* __restrict__ Wmu,
                                                   const float* __restrict__ Wlv,
                                                   unsigned short* __restrict__ Wp1,
                                                   unsigned short* __restrict__ Wp2) {
    int b = blockIdx.x;
    if (b < NB_E) {
        int e = b * 256 + threadIdx.x;
        if (e < E_EDGES) atomicAdd(&hist[__builtin_nontemporal_load(dst + e)], 1);
    } else {
        int i = (b - NB_E) * 256 + threadIdx.x;
        if (i < 256 * 128) {
            int k = i >> 7, n = i & 127;
            Wp1[n * 256 + k] = f2bf(W1[i]);
        }
        if (i < 128 * 128) {
            int k = i >> 7, n = i & 127;
            float w = (n < 64) ? Wmu[k * 64 + n] : Wlv[k * 64 + (n - 64)];
            Wp2[n * 128 + k] = f2bf(w);
        }
    }
}

// scan level 1 (+ dinv computed on the side)
__global__ __launch_bounds__(256) void k_scan1(const int* __restrict__ hist,
                                               int* __restrict__ offs,
                                               int* __restrict__ bsums,
                                               float* __restrict__ dinv) {
    __shared__ int sd[256];
    int t = threadIdx.x;
    int base = blockIdx.x * 1024 + t * 4;
    int v[4];
#pragma unroll
    for (int j = 0; j < 4; ++j) v[j] = (base + j < N_NODES) ? hist[base + j] : 0;
#pragma unroll
    for (int j = 0; j < 4; ++j)
        if (base + j < N_NODES) dinv[base + j] = rsqrtf((float)(v[j] + 1));
    int s = v[0] + v[1] + v[2] + v[3];
    sd[t] = s;
    __syncthreads();
    for (int d = 1; d < 256; d <<= 1) {
        int x = (t >= d) ? sd[t - d] : 0;
        __syncthreads();
        sd[t] += x;
        __syncthreads();
    }
    int excl = sd[t] - s;
    if (t == 255) bsums[blockIdx.x] = sd[255];
    int run = excl;
#pragma unroll
    for (int j = 0; j < 4; ++j) {
        if (base + j < N_NODES) offs[base + j] = run;
        run += v[j];
    }
}

__global__ __launch_bounds__(128) void k_scan2(int* __restrict__ bsums, int nb) {
    __shared__ int sd[128];
    int t = threadIdx.x;
    int v = (t < nb) ? bsums[t] : 0;
    sd[t] = v;
    __syncthreads();
    for (int d = 1; d < 128; d <<= 1) {
        int x = (t >= d) ? sd[t - d] : 0;
        __syncthreads();
        sd[t] += x;
        __syncthreads();
    }
    if (t < nb) bsums[t] = sd[t] - v;
}

// CSR fill; global offset = offs[d] + bsums[d>>10] folded here
__global__ __launch_bounds__(256) void k_fill(const int* __restrict__ src, const int* __restrict__ dst,
                                              const int* __restrict__ offs, const int* __restrict__ bsums,
                                              int* __restrict__ cursor,
                                              const float* __restrict__ dinv,
                                              int2* __restrict__ eidx) {
    int e = blockIdx.x * 256 + threadIdx.x;
    if (e < E_EDGES) {
        int s = __builtin_nontemporal_load(src + e);
        int d = __builtin_nontemporal_load(dst + e);
        int p = offs[d] + bsums[d >> 10] + atomicAdd(&cursor[d], 1);
        int2 v;
        v.x = s;
        v.y = __float_as_int(dinv[s] * dinv[d]);
        eidx[p] = v;
    }
}

// ---------------- GEMM1: h0[N][128] = bf16(x[N][256]) @ W1 ----------------
// Round-6 version (NT A-stage), unchanged -- dropped out of top-5 at <60 us.
__global__ __launch_bounds__(256, 6) void k_mgemm1(const float* __restrict__ A,
                                                   const unsigned short* __restrict__ Bpack,
                                                   unsigned short* __restrict__ out) {
    __shared__ float As[64 * 32];           // 8 KB, one K-chunk, swizzled
    __shared__ unsigned short Bs[128 * 40]; // 10 KB, padded stride 40
    int tid = threadIdx.x;
    int row0 = blockIdx.x * 64;
    int wave = tid >> 6, lane = tid & 63;
    int c = lane & 15, q = lane >> 4;
    int wrow = (wave >> 1) * 32, wcol = (wave & 1) * 64;

    float4v acc[2][4];
#pragma unroll
    for (int i = 0; i < 2; ++i)
#pragma unroll
        for (int j = 0; j < 4; ++j) acc[i][j] = (float4v){0.f, 0.f, 0.f, 0.f};

    int srow = tid >> 1;          // B stage: n-row
    int shalf = (tid & 1) * 16;   // B stage: k half

    for (int k0 = 0; k0 < 256; k0 += 32) {
        const unsigned short* bsrc = Bpack + (size_t)srow * 256 + k0 + shalf;
        short8 b0 = *(const short8*)(bsrc);
        short8 b1 = *(const short8*)(bsrc + 8);
#pragma unroll
        for (int t = 0; t < 2; ++t) {
            int grp = t * 4 + wave;               // 8 groups of 64 granules
            int S = grp * 64 + lane;              // slot in [0, 512)
            int row = S >> 3, j = S & 7;
            int kq = j ^ (row & 7);
            const float* g = A + (size_t)(row0 + row) * 256 + k0 + kq * 4;
            float* ldst = As + grp * 256;         // wave-uniform base
            if (row0 + row < N_NODES) ASYNC16NT(g, ldst);
        }
        *(short8*)(&Bs[srow * 40 + shalf])     = b0;
        *(short8*)(&Bs[srow * 40 + shalf + 8]) = b1;
        __syncthreads();

        short8 af[2], bfr[4];
#pragma unroll
        for (int mt = 0; mt < 2; ++mt) {
            int r = wrow + mt * 16 + c;
            int j0 = (q * 2) ^ (r & 7);
            float4v fa = *(const float4v*)(&As[r * 32 + j0 * 4]);        // k = q*8..+3
            float4v fb = *(const float4v*)(&As[r * 32 + (j0 ^ 1) * 4]);  // k = q*8+4..+7
            short8 s;
#pragma unroll
            for (int jj = 0; jj < 4; ++jj) s[jj]     = (short)f2bf(fa[jj]);
#pragma unroll
            for (int jj = 0; jj < 4; ++jj) s[4 + jj] = (short)f2bf(fb[jj]);
            af[mt] = s;
        }
#pragma unroll
        for (int nt = 0; nt < 4; ++nt)
            bfr[nt] = *(const short8*)(&Bs[(wcol + nt * 16 + c) * 40 + q * 8]);
#pragma unroll
        for (int mt = 0; mt < 2; ++mt)
#pragma unroll
            for (int nt = 0; nt < 4; ++nt)
                acc[mt][nt] = __builtin_amdgcn_mfma_f32_16x16x32_bf16(af[mt], bfr[nt], acc[mt][nt], 0, 0, 0);
        __syncthreads();
    }

    // epilogue: bf16 out. D: col = lane&15, row = q*4 + reg
#pragma unroll
    for (int mt = 0; mt < 2; ++mt) {
#pragma unroll
        for (int i = 0; i < 4; ++i) {
            int row = row0 + wrow + mt * 16 + q * 4 + i;
            if (row >= N_NODES) continue;
#pragma unroll
            for (int nt = 0; nt < 4; ++nt) {
                int cc = wcol + nt * 16 + c;
                out[(size_t)row * 128 + cc] = f2bf(acc[mt][nt][i]);
            }
        }
    }
}

// ---------------- aggregation layer 1: one wave per node (unchanged) ----------
__global__ __launch_bounds__(256) void k_agg1(const unsigned int* __restrict__ in,
                                              unsigned int* __restrict__ out,
                                              const float* __restrict__ dinv,
                                              const int2* __restrict__ eidx,
                                              const int* __restrict__ offs,
                                              const int* __restrict__ bsums,
                                              const int* __restrict__ cnt,
                                              const float* __restrict__ bias) {
    int wid = (blockIdx.x * 256 + threadIdx.x) >> 6;
    if (wid >= N_NODES) return;
    int l = threadIdx.x & 63;
    float di = dinv[wid];
    unsigned int u = in[(size_t)wid * 64 + l];
    float sc = di * di;
    float ax = sc * bf2f(u & 0xffffu) + bias[2 * l];
    float ay = sc * bf2f(u >> 16) + bias[2 * l + 1];
    int start = offs[wid] + bsums[wid >> 10];
    int n = cnt[wid];

    for (int base = 0; base < n; base += 64) {
        int m = min(n - base, 64);
        int sreg = 0; float wreg = 0.f;
        if (l < m) {
            int2 ev = eidx[start + base + l];
            sreg = ev.x;
            wreg = __int_as_float(ev.y);
        }
        int e = 0;
        for (; e + 4 <= m; e += 4) {
            int s0 = __shfl(sreg, e),     s1 = __shfl(sreg, e + 1);
            int s2 = __shfl(sreg, e + 2), s3 = __shfl(sreg, e + 3);
            float w0 = __shfl(wreg, e),     w1 = __shfl(wreg, e + 1);
            float w2 = __shfl(wreg, e + 2), w3 = __shfl(wreg, e + 3);
            unsigned int u0 = in[(size_t)s0 * 64 + l];
            unsigned int u1 = in[(size_t)s1 * 64 + l];
            unsigned int u2 = in[(size_t)s2 * 64 + l];
            unsigned int u3 = in[(size_t)s3 * 64 + l];
            ax += w0 * bf2f(u0 & 0xffffu); ay += w0 * bf2f(u0 >> 16);
            ax += w1 * bf2f(u1 & 0xffffu); ay += w1 * bf2f(u1 >> 16);
            ax += w2 * bf2f(u2 & 0xffffu); ay += w2 * bf2f(u2 >> 16);
            ax += w3 * bf2f(u3 & 0xffffu); ay += w3 * bf2f(u3 >> 16);
        }
        for (; e < m; ++e) {
            int s0 = __shfl(sreg, e);
            float w0 = __shfl(wreg, e);
            unsigned int u0 = in[(size_t)s0 * 64 + l];
            ax += w0 * bf2f(u0 & 0xffffu); ay += w0 * bf2f(u0 >> 16);
        }
    }
    ax = fmaxf(ax, 0.f); ay = fmaxf(ay, 0.f);
    out[(size_t)wid * 64 + l] = (unsigned int)f2bf(ax) | ((unsigned int)f2bf(ay) << 16);
}

// ---------------- FUSED: g = A_hat h ; [mu|logvar] = g @ W2 + bias ----------
// Per 64-node block (512 thr, 8 waves): phase 1 -- each wave runs the proven
// agg loop for 8 nodes, writing g rows as bf16 DIRECTLY into LDS in mgemm2's
// [4 chunks][64 rows][40] A-layout (skips the 25.6 MB g write + 25.6 MB
// re-read at the ~1.5 TB/s poisoned-read wall). Phase 2 -- proven mgemm2
// K-loop verbatim: per-chunk B stage, MFMA, proven epilogue, regular stores.
// LDS 30 KB -> 4 blocks/CU = 32 waves/CU (same latency hiding as standalone agg).
__global__ __launch_bounds__(512, 8) void k_agg2mm(const unsigned int* __restrict__ in,
                                                   const float* __restrict__ dinv,
                                                   const int2* __restrict__ eidx,
                                                   const int* __restrict__ offs,
                                                   const int* __restrict__ bsums,
                                                   const int* __restrict__ cnt,
                                                   const unsigned short* __restrict__ Bpack,
                                                   const float* __restrict__ bias0,
                                                   const float* __restrict__ bias1,
                                                   float* __restrict__ out) {
    __shared__ unsigned short As4[4 * 64 * 40];   // 20 KB: [chunk][row][40]
    __shared__ unsigned short Bs[128 * 40];       // 10 KB
    int tid = threadIdx.x;
    int row0 = blockIdx.x * 64;
    int wave = tid >> 6, lane = tid & 63;
    int l = lane;

    // ---- phase 1: aggregate 8 nodes per wave into LDS ----
    unsigned int* As4w = (unsigned int*)As4;
    int ui = (l >> 4) * 1280 + (l & 15);          // chunk*1280 + col pairs
#pragma unroll 1
    for (int i = 0; i < 8; ++i) {
        int lr = wave * 8 + i;                    // local row 0..63
        int nd = row0 + lr;
        float ax = 0.f, ay = 0.f;
        if (nd < N_NODES) {
            float di = dinv[nd];
            unsigned int u = in[(size_t)nd * 64 + l];
            float sc = di * di;
            ax = sc * bf2f(u & 0xffffu);
            ay = sc * bf2f(u >> 16);
            int start = offs[nd] + bsums[nd >> 10];
            int n = cnt[nd];
            for (int base = 0; base < n; base += 64) {
                int m = min(n - base, 64);
                int sreg = 0; float wreg = 0.f;
                if (l < m) {
                    int2 ev = eidx[start + base + l];
                    sreg = ev.x;
                    wreg = __int_as_float(ev.y);
                }
                int e = 0;
                for (; e + 4 <= m; e += 4) {
                    int s0 = __shfl(sreg, e),     s1 = __shfl(sreg, e + 1);
                    int s2 = __shfl(sreg, e + 2), s3 = __shfl(sreg, e + 3);
                    float w0 = __shfl(wreg, e),     w1 = __shfl(wreg, e + 1);
                    float w2 = __shfl(wreg, e + 2), w3 = __shfl(wreg, e + 3);
                    unsigned int u0 = in[(size_t)s0 * 64 + l];
                    unsigned int u1 = in[(size_t)s1 * 64 + l];
                    unsigned int u2 = in[(size_t)s2 * 64 + l];
                    unsigned int u3 = in[(size_t)s3 * 64 + l];
                    ax += w0 * bf2f(u0 & 0xffffu); ay += w0 * bf2f(u0 >> 16);
                    ax += w1 * bf2f(u1 & 0xffffu); ay += w1 * bf2f(u1 >> 16);
                    ax += w2 * bf2f(u2 & 0xffffu); ay += w2 * bf2f(u2 >> 16);
                    ax += w3 * bf2f(u3 & 0xffffu); ay += w3 * bf2f(u3 >> 16);
                }
                for (; e < m; ++e) {
                    int s0 = __shfl(sreg, e);
                    float w0 = __shfl(wreg, e);
                    unsigned int u0 = in[(size_t)s0 * 64 + l];
                    ax += w0 * bf2f(u0 & 0xffffu); ay += w0 * bf2f(u0 >> 16);
                }
            }
        }
        As4w[ui + lr * 20] = (unsigned int)f2bf(ax) | ((unsigned int)f2bf(ay) << 16);
    }

    // ---- phase 2: [64][128] @ [128][128] via MFMA (proven mgemm2 loop) ----
    int c = lane & 15, q = lane >> 4;
    int wm = wave >> 2, wn = wave & 3;            // 2 x 4 wave grid
    int wrow = wm * 32, wcol = wn * 32;

    float4v acc[2][2];
#pragma unroll
    for (int i = 0; i < 2; ++i)
#pragma unroll
        for (int j = 0; j < 2; ++j) acc[i][j] = (float4v){0.f, 0.f, 0.f, 0.f};

    int srow = tid >> 2;               // B stage: 128 rows, 4 threads/row
    int soff = (tid & 3) * 8;          // 16B each

    for (int kc = 0; kc < 4; ++kc) {
        int k0 = kc * 32;
        short8 b0 = *(const short8*)(Bpack + (size_t)srow * 128 + k0 + soff);
        __syncthreads();               // As4 ready (first iter) / Bs consumed
        *(short8*)(&Bs[srow * 40 + soff]) = b0;
        __syncthreads();

        short8 af[2], bfr[2];
#pragma unroll
        for (int mt = 0; mt < 2; ++mt)
            af[mt] = *(const short8*)(&As4[kc * 2560 + (wrow + mt * 16 + c) * 40 + q * 8]);
#pragma unroll
        for (int nt = 0; nt < 2; ++nt)
            bfr[nt] = *(const short8*)(&Bs[(wcol + nt * 16 + c) * 40 + q * 8]);
#pragma unroll
        for (int mt = 0; mt < 2; ++mt)
#pragma unroll
            for (int nt = 0; nt < 2; ++nt)
                acc[mt][nt] = __builtin_amdgcn_mfma_f32_16x16x32_bf16(af[mt], bfr[nt], acc[mt][nt], 0, 0, 0);
    }

    // epilogue: mu at 0, logvar at N*64 (regular stores -- round-5 lesson)
#pragma unroll
    for (int mt = 0; mt < 2; ++mt) {
#pragma unroll
        for (int i = 0; i < 4; ++i) {
            int row = row0 + wrow + mt * 16 + q * 4 + i;
            if (row >= N_NODES) continue;
#pragma unroll
            for (int nt = 0; nt < 2; ++nt) {
                int cc = wcol + nt * 16 + c;
                float v = acc[mt][nt][i];
                if (cc < 64) out[(size_t)row * 64 + cc] = v + bias0[cc];
                else out[(size_t)N_NODES * 64 + (size_t)row * 64 + (cc - 64)] = v + bias1[cc - 64];
            }
        }
    }
}

// ---------------- launch ----------------
extern "C" void kernel_launch(void* const* d_in, const int* in_sizes, int n_in,
                              void* d_out, int out_size, void* d_ws, size_t ws_size,
                              hipStream_t stream) {
    const float* x    = (const float*)d_in[0];
    const int*   ei   = (const int*)d_in[1];
    const float* W1   = (const float*)d_in[2];
    const float* b1   = (const float*)d_in[3];
    const float* Wmu  = (const float*)d_in[4];
    const float* bmu  = (const float*)d_in[5];
    const float* Wlv  = (const float*)d_in[6];
    const float* blv  = (const float*)d_in[7];
    float* outp = (float*)d_out;

    const int* src = ei;
    const int* dst = ei + E_EDGES;

    char* ws = (char*)d_ws;
    int*            hist   = (int*)(ws + WS_HIST);
    int*            cursor = (int*)(ws + WS_CURSOR);
    int*            offs   = (int*)(ws + WS_OFFS);
    float*          dinv   = (float*)(ws + WS_DINV);
    int*            bsums  = (int*)(ws + WS_BSUMS);
    int2*           eidx   = (int2*)(ws + WS_EIDX);
    unsigned short* Wp1    = (unsigned short*)(ws + WS_WP1);
    unsigned short* Wp2    = (unsigned short*)(ws + WS_WP2);
    unsigned short* h0     = (unsigned short*)(ws + WS_H0);   // x@W1
    unsigned short* h      = (unsigned short*)(ws + WS_H);    // relu(A_hat h0 + b1)

    const int NB_S = (N_NODES + 1023) / 1024;   // 98
    const int NB_G = (N_NODES + 63) / 64;       // 1563

    hipMemsetAsync(ws + WS_HIST, 0, 1048576, stream);   // hist + cursor
    k_hist_pack<<<NB_E + 128, 256, 0, stream>>>(dst, hist, W1, Wmu, Wlv, Wp1, Wp2);
    k_scan1<<<NB_S, 256, 0, stream>>>(hist, offs, bsums, dinv);
    k_scan2<<<1, 128, 0, stream>>>(bsums, NB_S);
    k_fill<<<NB_E, 256, 0, stream>>>(src, dst, offs, bsums, cursor, dinv, eidx);

    // layer 1: h0 = bf16(x) @ W1 ; h = relu(A_hat h0 + b1)
    k_mgemm1<<<NB_G, 256, 0, stream>>>(x, Wp1, h0);
    k_agg1<<<(N_NODES * 64 + 255) / 256, 256, 0, stream>>>(
        (const unsigned int*)h0, (unsigned int*)h, dinv, eidx, offs, bsums, hist, b1);

    // layers 2+3 fused: g = A_hat h (in LDS) ; [mu|logvar] = g @ W2 + bias
    k_agg2mm<<<NB_G, 512, 0, stream>>>(
        (const unsigned int*)h, dinv, eidx, offs, bsums, hist, Wp2, bmu, blv, outp);
}

// Round 8
// 336.742 us; speedup vs baseline: 1.1118x; 1.0069x over previous
//
#include <hip/hip_runtime.h>
#include <hip/hip_bf16.h>

#define N_NODES 100000
#define E_EDGES 640000
// channels: IN 256, HID 128, OUT 64+64

typedef __attribute__((ext_vector_type(8))) short short8;
typedef __attribute__((ext_vector_type(4))) float float4v;

__device__ __forceinline__ float bf2f(unsigned int u16) {
    union { unsigned int i; float f; } c; c.i = u16 << 16; return c.f;
}
__device__ __forceinline__ unsigned short f2bf(float f) {
    union { float f; unsigned int i; } c; c.f = f;
    unsigned int x = c.i;
    unsigned int r = (x + 0x7fffu + ((x >> 16) & 1u)) >> 16;   // RNE
    return (unsigned short)r;
}

// async 16B global->LDS; aux = CPol bits (bit1 = NT). ONLY on pure inputs (x):
// NT on cache-dirty buffers (workspace/output) is a correctness hazard (round 5).
#define ASYNC16NT(g, l)                                                        \
    __builtin_amdgcn_global_load_lds(                                          \
        (const __attribute__((address_space(1))) void*)(g),                    \
        (__attribute__((address_space(3))) void*)(l), 16, 0, 2)

// ---------------- workspace layout (bytes) ----------------
#define WS_HIST    0          // int[100000]
#define WS_CURSOR  524288     // int[100000]
#define WS_DONE    1048512    // int  (zeroed by the same memset: < 1 MB)
#define WS_OFFS    1048576    // int[100000]
#define WS_DINV    1572864    // float[100000]
#define WS_BSUMS   2097152    // int[256]
#define WS_EIDX    2621440    // int2[640000]  {src, bits(weight)}
#define WS_WP1     7864320    // bf16[128][256] packed W1^T
#define WS_WP2     7929856    // bf16[128][128] packed [Wmu|Wlv]^T
#define WS_H0      7962624    // bf16[100000*128]  x@W1
#define WS_H       33562624   // bf16[100000*128]  relu(A_hat h0 + b1)

// ---------------- setup: histogram + weight pack (fused, independent work) ----
#define NB_E 2500
#define NB_G 1563             // (N_NODES+63)/64
__global__ __launch_bounds__(256) void k_hist_pack(const int* __restrict__ dst, int* __restrict__ hist,
                                                   const float* __restrict__ W1,
                                                   const float* __restrict__ Wmu,
                                                   const float* __restrict__ Wlv,
                                                   unsigned short* __restrict__ Wp1,
                                                   unsigned short* __restrict__ Wp2) {
    int b = blockIdx.x;
    if (b < NB_E) {
        int e = b * 256 + threadIdx.x;
        if (e < E_EDGES) atomicAdd(&hist[__builtin_nontemporal_load(dst + e)], 1);
    } else {
        int i = (b - NB_E) * 256 + threadIdx.x;
        if (i < 256 * 128) {
            int k = i >> 7, n = i & 127;
            Wp1[n * 256 + k] = f2bf(W1[i]);
        }
        if (i < 128 * 128) {
            int k = i >> 7, n = i & 127;
            float w = (n < 64) ? Wmu[k * 64 + n] : Wlv[k * 64 + (n - 64)];
            Wp2[n * 128 + k] = f2bf(w);
        }
    }
}

// scan level 1 (+ dinv) with last-block-done fold of the level-2 scan:
// bsums traffic is all device-scope atomics; the vmcnt(0) drain the compiler
// emits before s_barrier orders the atomicExch before the done-counter bump.
__global__ __launch_bounds__(256) void k_scan1(const int* __restrict__ hist,
                                               int* __restrict__ offs,
                                               int* __restrict__ bsums,
                                               float* __restrict__ dinv,
                                               int* __restrict__ done) {
    __shared__ int sd[256];
    __shared__ int isLast;
    int t = threadIdx.x;
    int base = blockIdx.x * 1024 + t * 4;
    int v[4];
#pragma unroll
    for (int j = 0; j < 4; ++j) v[j] = (base + j < N_NODES) ? hist[base + j] : 0;
#pragma unroll
    for (int j = 0; j < 4; ++j)
        if (base + j < N_NODES) dinv[base + j] = rsqrtf((float)(v[j] + 1));
    int s = v[0] + v[1] + v[2] + v[3];
    sd[t] = s;
    __syncthreads();
    for (int d = 1; d < 256; d <<= 1) {
        int x = (t >= d) ? sd[t - d] : 0;
        __syncthreads();
        sd[t] += x;
        __syncthreads();
    }
    int excl = sd[t] - s;
    if (t == 255) atomicExch(&bsums[blockIdx.x], sd[255]);
    int run = excl;
#pragma unroll
    for (int j = 0; j < 4; ++j) {
        if (base + j < N_NODES) offs[base + j] = run;
        run += v[j];
    }
    __syncthreads();                      // drains the atomicExch (vmcnt(0))
    if (t == 0) isLast = (atomicAdd(done, 1) == (int)gridDim.x - 1);
    __syncthreads();
    if (isLast) {
        int nb = gridDim.x;               // 98
        int bv = (t < nb) ? atomicAdd(&bsums[t], 0) : 0;   // coherent read
        sd[t] = bv;
        __syncthreads();
        for (int d = 1; d < 256; d <<= 1) {
            int x = (t >= d) ? sd[t - d] : 0;
            __syncthreads();
            sd[t] += x;
            __syncthreads();
        }
        if (t < nb) atomicExch(&bsums[t], sd[t] - bv);     // exclusive
    }
}

// ---------------- MERGED: GEMM1 (blocks 0..NB_G) + CSR fill (rest) ----------
// Independent work, complementary bottlenecks: mgemm1 is read-BW-bound on x,
// fill is scatter/atomic latency-bound -- fill hides under mgemm1's shadow.
__global__ __launch_bounds__(256, 6) void k_mm1_fill(const float* __restrict__ A,
                                                     const unsigned short* __restrict__ Bpack,
                                                     unsigned short* __restrict__ out,
                                                     const int* __restrict__ src, const int* __restrict__ dst,
                                                     const int* __restrict__ offs, const int* __restrict__ bsums,
                                                     int* __restrict__ cursor,
                                                     const float* __restrict__ dinv,
                                                     int2* __restrict__ eidx) {
    __shared__ float As[64 * 32];           // 8 KB, one K-chunk, swizzled
    __shared__ unsigned short Bs[128 * 40]; // 10 KB, padded stride 40

    if (blockIdx.x >= NB_G) {
        // ---- CSR fill branch ----
        int e = (blockIdx.x - NB_G) * 256 + threadIdx.x;
        if (e < E_EDGES) {
            int s = __builtin_nontemporal_load(src + e);
            int d = __builtin_nontemporal_load(dst + e);
            int p = offs[d] + bsums[d >> 10] + atomicAdd(&cursor[d], 1);
            int2 v;
            v.x = s;
            v.y = __float_as_int(dinv[s] * dinv[d]);
            eidx[p] = v;
        }
        return;
    }

    // ---- GEMM1 branch (round-6 body verbatim, NT A-stage) ----
    int tid = threadIdx.x;
    int row0 = blockIdx.x * 64;
    int wave = tid >> 6, lane = tid & 63;
    int c = lane & 15, q = lane >> 4;
    int wrow = (wave >> 1) * 32, wcol = (wave & 1) * 64;

    float4v acc[2][4];
#pragma unroll
    for (int i = 0; i < 2; ++i)
#pragma unroll
        for (int j = 0; j < 4; ++j) acc[i][j] = (float4v){0.f, 0.f, 0.f, 0.f};

    int srow = tid >> 1;          // B stage: n-row
    int shalf = (tid & 1) * 16;   // B stage: k half

    for (int k0 = 0; k0 < 256; k0 += 32) {
        const unsigned short* bsrc = Bpack + (size_t)srow * 256 + k0 + shalf;
        short8 b0 = *(const short8*)(bsrc);
        short8 b1 = *(const short8*)(bsrc + 8);
#pragma unroll
        for (int t = 0; t < 2; ++t) {
            int grp = t * 4 + wave;               // 8 groups of 64 granules
            int S = grp * 64 + lane;              // slot in [0, 512)
            int row = S >> 3, j = S & 7;
            int kq = j ^ (row & 7);
            const float* g = A + (size_t)(row0 + row) * 256 + k0 + kq * 4;
            float* ldst = As + grp * 256;         // wave-uniform base
            if (row0 + row < N_NODES) ASYNC16NT(g, ldst);
        }
        *(short8*)(&Bs[srow * 40 + shalf])     = b0;
        *(short8*)(&Bs[srow * 40 + shalf + 8]) = b1;
        __syncthreads();

        short8 af[2], bfr[4];
#pragma unroll
        for (int mt = 0; mt < 2; ++mt) {
            int r = wrow + mt * 16 + c;
            int j0 = (q * 2) ^ (r & 7);
            float4v fa = *(const float4v*)(&As[r * 32 + j0 * 4]);        // k = q*8..+3
            float4v fb = *(const float4v*)(&As[r * 32 + (j0 ^ 1) * 4]);  // k = q*8+4..+7
            short8 s;
#pragma unroll
            for (int jj = 0; jj < 4; ++jj) s[jj]     = (short)f2bf(fa[jj]);
#pragma unroll
            for (int jj = 0; jj < 4; ++jj) s[4 + jj] = (short)f2bf(fb[jj]);
            af[mt] = s;
        }
#pragma unroll
        for (int nt = 0; nt < 4; ++nt)
            bfr[nt] = *(const short8*)(&Bs[(wcol + nt * 16 + c) * 40 + q * 8]);
#pragma unroll
        for (int mt = 0; mt < 2; ++mt)
#pragma unroll
            for (int nt = 0; nt < 4; ++nt)
                acc[mt][nt] = __builtin_amdgcn_mfma_f32_16x16x32_bf16(af[mt], bfr[nt], acc[mt][nt], 0, 0, 0);
        __syncthreads();
    }

    // epilogue: bf16 out. D: col = lane&15, row = q*4 + reg
#pragma unroll
    for (int mt = 0; mt < 2; ++mt) {
#pragma unroll
        for (int i = 0; i < 4; ++i) {
            int row = row0 + wrow + mt * 16 + q * 4 + i;
            if (row >= N_NODES) continue;
#pragma unroll
            for (int nt = 0; nt < 4; ++nt) {
                int cc = wcol + nt * 16 + c;
                out[(size_t)row * 128 + cc] = f2bf(acc[mt][nt][i]);
            }
        }
    }
}

// ---------------- aggregation layer 1: one wave per node (unchanged) ----------
__global__ __launch_bounds__(256) void k_agg1(const unsigned int* __restrict__ in,
                                              unsigned int* __restrict__ out,
                                              const float* __restrict__ dinv,
                                              const int2* __restrict__ eidx,
                                              const int* __restrict__ offs,
                                              const int* __restrict__ bsums,
                                              const int* __restrict__ cnt,
                                              const float* __restrict__ bias) {
    int wid = (blockIdx.x * 256 + threadIdx.x) >> 6;
    if (wid >= N_NODES) return;
    int l = threadIdx.x & 63;
    float di = dinv[wid];
    unsigned int u = in[(size_t)wid * 64 + l];
    float sc = di * di;
    float ax = sc * bf2f(u & 0xffffu) + bias[2 * l];
    float ay = sc * bf2f(u >> 16) + bias[2 * l + 1];
    int start = offs[wid] + bsums[wid >> 10];
    int n = cnt[wid];

    for (int base = 0; base < n; base += 64) {
        int m = min(n - base, 64);
        int sreg = 0; float wreg = 0.f;
        if (l < m) {
            int2 ev = eidx[start + base + l];
            sreg = ev.x;
            wreg = __int_as_float(ev.y);
        }
        int e = 0;
        for (; e + 4 <= m; e += 4) {
            int s0 = __shfl(sreg, e),     s1 = __shfl(sreg, e + 1);
            int s2 = __shfl(sreg, e + 2), s3 = __shfl(sreg, e + 3);
            float w0 = __shfl(wreg, e),     w1 = __shfl(wreg, e + 1);
            float w2 = __shfl(wreg, e + 2), w3 = __shfl(wreg, e + 3);
            unsigned int u0 = in[(size_t)s0 * 64 + l];
            unsigned int u1 = in[(size_t)s1 * 64 + l];
            unsigned int u2 = in[(size_t)s2 * 64 + l];
            unsigned int u3 = in[(size_t)s3 * 64 + l];
            ax += w0 * bf2f(u0 & 0xffffu); ay += w0 * bf2f(u0 >> 16);
            ax += w1 * bf2f(u1 & 0xffffu); ay += w1 * bf2f(u1 >> 16);
            ax += w2 * bf2f(u2 & 0xffffu); ay += w2 * bf2f(u2 >> 16);
            ax += w3 * bf2f(u3 & 0xffffu); ay += w3 * bf2f(u3 >> 16);
        }
        for (; e < m; ++e) {
            int s0 = __shfl(sreg, e);
            float w0 = __shfl(wreg, e);
            unsigned int u0 = in[(size_t)s0 * 64 + l];
            ax += w0 * bf2f(u0 & 0xffffu); ay += w0 * bf2f(u0 >> 16);
        }
    }
    ax = fmaxf(ax, 0.f); ay = fmaxf(ay, 0.f);
    out[(size_t)wid * 64 + l] = (unsigned int)f2bf(ax) | ((unsigned int)f2bf(ay) << 16);
}

// ---------------- FUSED: g = A_hat h ; [mu|logvar] = g @ W2 + bias ----------
// Round-7 version (proven): agg into LDS A-layout, then mgemm2 K-loop.
__global__ __launch_bounds__(512, 8) void k_agg2mm(const unsigned int* __restrict__ in,
                                                   const float* __restrict__ dinv,
                                                   const int2* __restrict__ eidx,
                                                   const int* __restrict__ offs,
                                                   const int* __restrict__ bsums,
                                                   const int* __restrict__ cnt,
                                                   const unsigned short* __restrict__ Bpack,
                                                   const float* __restrict__ bias0,
                                                   const float* __restrict__ bias1,
                                                   float* __restrict__ out) {
    __shared__ unsigned short As4[4 * 64 * 40];   // 20 KB: [chunk][row][40]
    __shared__ unsigned short Bs[128 * 40];       // 10 KB
    int tid = threadIdx.x;
    int row0 = blockIdx.x * 64;
    int wave = tid >> 6, lane = tid & 63;
    int l = lane;

    // ---- phase 1: aggregate 8 nodes per wave into LDS ----
    unsigned int* As4w = (unsigned int*)As4;
    int ui = (l >> 4) * 1280 + (l & 15);          // chunk*1280 + col pairs
#pragma unroll 1
    for (int i = 0; i < 8; ++i) {
        int lr = wave * 8 + i;                    // local row 0..63
        int nd = row0 + lr;
        float ax = 0.f, ay = 0.f;
        if (nd < N_NODES) {
            float di = dinv[nd];
            unsigned int u = in[(size_t)nd * 64 + l];
            float sc = di * di;
            ax = sc * bf2f(u & 0xffffu);
            ay = sc * bf2f(u >> 16);
            int start = offs[nd] + bsums[nd >> 10];
            int n = cnt[nd];
            for (int base = 0; base < n; base += 64) {
                int m = min(n - base, 64);
                int sreg = 0; float wreg = 0.f;
                if (l < m) {
                    int2 ev = eidx[start + base + l];
                    sreg = ev.x;
                    wreg = __int_as_float(ev.y);
                }
                int e = 0;
                for (; e + 4 <= m; e += 4) {
                    int s0 = __shfl(sreg, e),     s1 = __shfl(sreg, e + 1);
                    int s2 = __shfl(sreg, e + 2), s3 = __shfl(sreg, e + 3);
                    float w0 = __shfl(wreg, e),     w1 = __shfl(wreg, e + 1);
                    float w2 = __shfl(wreg, e + 2), w3 = __shfl(wreg, e + 3);
                    unsigned int u0 = in[(size_t)s0 * 64 + l];
                    unsigned int u1 = in[(size_t)s1 * 64 + l];
                    unsigned int u2 = in[(size_t)s2 * 64 + l];
                    unsigned int u3 = in[(size_t)s3 * 64 + l];
                    ax += w0 * bf2f(u0 & 0xffffu); ay += w0 * bf2f(u0 >> 16);
                    ax += w1 * bf2f(u1 & 0xffffu); ay += w1 * bf2f(u1 >> 16);
                    ax += w2 * bf2f(u2 & 0xffffu); ay += w2 * bf2f(u2 >> 16);
                    ax += w3 * bf2f(u3 & 0xffffu); ay += w3 * bf2f(u3 >> 16);
                }
                for (; e < m; ++e) {
                    int s0 = __shfl(sreg, e);
                    float w0 = __shfl(wreg, e);
                    unsigned int u0 = in[(size_t)s0 * 64 + l];
                    ax += w0 * bf2f(u0 & 0xffffu); ay += w0 * bf2f(u0 >> 16);
                }
            }
        }
        As4w[ui + lr * 20] = (unsigned int)f2bf(ax) | ((unsigned int)f2bf(ay) << 16);
    }

    // ---- phase 2: [64][128] @ [128][128] via MFMA (proven mgemm2 loop) ----
    int c = lane & 15, q = lane >> 4;
    int wm = wave >> 2, wn = wave & 3;            // 2 x 4 wave grid
    int wrow = wm * 32, wcol = wn * 32;

    float4v acc[2][2];
#pragma unroll
    for (int i = 0; i < 2; ++i)
#pragma unroll
        for (int j = 0; j < 2; ++j) acc[i][j] = (float4v){0.f, 0.f, 0.f, 0.f};

    int srow = tid >> 2;               // B stage: 128 rows, 4 threads/row
    int soff = (tid & 3) * 8;          // 16B each

    for (int kc = 0; kc < 4; ++kc) {
        int k0 = kc * 32;
        short8 b0 = *(const short8*)(Bpack + (size_t)srow * 128 + k0 + soff);
        __syncthreads();               // As4 ready (first iter) / Bs consumed
        *(short8*)(&Bs[srow * 40 + soff]) = b0;
        __syncthreads();

        short8 af[2], bfr[2];
#pragma unroll
        for (int mt = 0; mt < 2; ++mt)
            af[mt] = *(const short8*)(&As4[kc * 2560 + (wrow + mt * 16 + c) * 40 + q * 8]);
#pragma unroll
        for (int nt = 0; nt < 2; ++nt)
            bfr[nt] = *(const short8*)(&Bs[(wcol + nt * 16 + c) * 40 + q * 8]);
#pragma unroll
        for (int mt = 0; mt < 2; ++mt)
#pragma unroll
            for (int nt = 0; nt < 2; ++nt)
                acc[mt][nt] = __builtin_amdgcn_mfma_f32_16x16x32_bf16(af[mt], bfr[nt], acc[mt][nt], 0, 0, 0);
    }

    // epilogue: mu at 0, logvar at N*64 (regular stores -- round-5 lesson)
#pragma unroll
    for (int mt = 0; mt < 2; ++mt) {
#pragma unroll
        for (int i = 0; i < 4; ++i) {
            int row = row0 + wrow + mt * 16 + q * 4 + i;
            if (row >= N_NODES) continue;
#pragma unroll
            for (int nt = 0; nt < 2; ++nt) {
                int cc = wcol + nt * 16 + c;
                float v = acc[mt][nt][i];
                if (cc < 64) out[(size_t)row * 64 + cc] = v + bias0[cc];
                else out[(size_t)N_NODES * 64 + (size_t)row * 64 + (cc - 64)] = v + bias1[cc - 64];
            }
        }
    }
}

// ---------------- launch ----------------
extern "C" void kernel_launch(void* const* d_in, const int* in_sizes, int n_in,
                              void* d_out, int out_size, void* d_ws, size_t ws_size,
                              hipStream_t stream) {
    const float* x    = (const float*)d_in[0];
    const int*   ei   = (const int*)d_in[1];
    const float* W1   = (const float*)d_in[2];
    const float* b1   = (const float*)d_in[3];
    const float* Wmu  = (const float*)d_in[4];
    const float* bmu  = (const float*)d_in[5];
    const float* Wlv  = (const float*)d_in[6];
    const float* blv  = (const float*)d_in[7];
    float* outp = (float*)d_out;

    const int* src = ei;
    const int* dst = ei + E_EDGES;

    char* ws = (char*)d_ws;
    int*            hist   = (int*)(ws + WS_HIST);
    int*            cursor = (int*)(ws + WS_CURSOR);
    int*            done   = (int*)(ws + WS_DONE);
    int*            offs   = (int*)(ws + WS_OFFS);
    float*          dinv   = (float*)(ws + WS_DINV);
    int*            bsums  = (int*)(ws + WS_BSUMS);
    int2*           eidx   = (int2*)(ws + WS_EIDX);
    unsigned short* Wp1    = (unsigned short*)(ws + WS_WP1);
    unsigned short* Wp2    = (unsigned short*)(ws + WS_WP2);
    unsigned short* h0     = (unsigned short*)(ws + WS_H0);   // x@W1
    unsigned short* h      = (unsigned short*)(ws + WS_H);    // relu(A_hat h0 + b1)

    const int NB_S = (N_NODES + 1023) / 1024;   // 98

    hipMemsetAsync(ws + WS_HIST, 0, 1048576, stream);   // hist + cursor + done
    k_hist_pack<<<NB_E + 128, 256, 0, stream>>>(dst, hist, W1, Wmu, Wlv, Wp1, Wp2);
    k_scan1<<<NB_S, 256, 0, stream>>>(hist, offs, bsums, dinv, done);

    // merged: GEMM1 (h0 = bf16(x)@W1) overlapped with CSR fill
    k_mm1_fill<<<NB_G + NB_E, 256, 0, stream>>>(x, Wp1, h0,
                                                src, dst, offs, bsums, cursor, dinv, eidx);

    // layer 1 agg: h = relu(A_hat h0 + b1)
    k_agg1<<<(N_NODES * 64 + 255) / 256, 256, 0, stream>>>(
        (const unsigned int*)h0, (unsigned int*)h, dinv, eidx, offs, bsums, hist, b1);

    // layers 2+3 fused: g = A_hat h (in LDS) ; [mu|logvar] = g @ W2 + bias
    k_agg2mm<<<NB_G, 512, 0, stream>>>(
        (const unsigned int*)h, dinv, eidx, offs, bsums, hist, Wp2, bmu, blv, outp);
}